// Round 9
// baseline (67.553 us; speedup 1.0000x reference)
//
#include <hip/hip_runtime.h>

// Problem constants (match reference)
#define TB 8
#define TT 400
#define TS 40
#define TV 512
#define SU (TS + 1)          // 41
#define NROWS (TB * TT * SU) // 131200
#define SS 8                 // t-steps per superstep
#define NSS (TT / SS)        // 50 supersteps
#define NW (SS + 1)          // 9 path weights per superstep (j = 0..8)
#define WGRP 5               // supersteps per pipeline group
#define NGRP (NSS / WGRP)    // 10 groups
#define NEG_INF (-1.0e30f)
#define INV_LN2 1.44269504088896341f
#define LN2 0.69314718055994531f

// VALU whole-wave shift-up-by-1 (DPP wave_shr:1); lane 0 sources 0 (harmless).
__device__ __forceinline__ float wave_shr1(float x) {
    return __int_as_float(
        __builtin_amdgcn_update_dpp(0, __float_as_int(x), 0x138, 0xf, 0xf, true));
}

// base-2 logaddexp (lp values live in log2 domain)
__device__ __forceinline__ float lse2(float a, float c) {
    const float mx = fmaxf(a, c), mn = fminf(a, c);
    return mx + __builtin_amdgcn_logf(1.0f + __builtin_amdgcn_exp2f(mn - mx));
}

// ---------------- kernel 1: per-row log-sum-exp (HBM-bound, ~40us) ----------
__global__ __launch_bounds__(256) void rowlse_kernel(
    const float* __restrict__ acts, const int* __restrict__ labels,
    float* __restrict__ lp_blank, float* __restrict__ lp_label)
{
    const int wave = threadIdx.x >> 6;
    const int lane = threadIdx.x & 63;
    const int row  = blockIdx.x * 4 + wave;   // grid*4 == NROWS exactly

    const float* rp = acts + (size_t)row * TV;
    float4 a = *(const float4*)(rp + lane * 8);
    float4 b = *(const float4*)(rp + lane * 8 + 4);

    float m = fmaxf(fmaxf(fmaxf(a.x, a.y), fmaxf(a.z, a.w)),
                    fmaxf(fmaxf(b.x, b.y), fmaxf(b.z, b.w)));
#pragma unroll
    for (int off = 1; off < 64; off <<= 1) m = fmaxf(m, __shfl_xor(m, off));

    float s = __expf(a.x - m) + __expf(a.y - m) + __expf(a.z - m) + __expf(a.w - m)
            + __expf(b.x - m) + __expf(b.y - m) + __expf(b.z - m) + __expf(b.w - m);
#pragma unroll
    for (int off = 1; off < 64; off <<= 1) s += __shfl_xor(s, off);

    const float logZ = m + logf(s);

    if (lane == 0) {
        const int u  = row % SU;
        const int bt = row / SU;
        lp_blank[row] = (a.x - logZ) * INV_LN2;          // log2 domain
        if (u < TS) {
            const int b_idx = bt / TT;
            const int col   = labels[b_idx * TS + u];
            lp_label[bt * TS + u] = (rp[col] - logZ) * INV_LN2;
        }
    }
}

// compose superstep s of batch b into dstW[NW][SU] (LDS slice).
// In-register DP over the 8 steps (identical math to R8's compose, absmax 0):
// E[j] <- LSE2( E[j]+b_m , shr1(E[j-1])+l_m ), j descending.
__device__ __forceinline__ void compose8(
    const float* __restrict__ lp_blank, const float* __restrict__ lp_label,
    int b, int s, int lane, float* dstW)
{
    const int t0 = s * SS;
    const int uu = (lane <= TS) ? lane : TS;               // clamp loads
    const bool have_l = (lane >= 1 && lane <= TS);

    const float* pb = lp_blank + ((size_t)b * TT + t0) * SU + uu;
    const float* pl = lp_label + ((size_t)b * TT + t0) * TS + (have_l ? lane - 1 : 0);

    float bm[SS], lm[SS];
#pragma unroll
    for (int m = 0; m < SS; ++m) {
        bm[m] = pb[m * SU];
        float lv = pl[m * TS];
        lm[m] = have_l ? lv : NEG_INF;   // u=0 / u>TS: move-into-u invalid
    }

    float E[NW];
    E[0] = 0.0f;
#pragma unroll
    for (int j = 1; j < NW; ++j) E[j] = NEG_INF;

#pragma unroll
    for (int m = 0; m < SS; ++m) {
#pragma unroll
        for (int jj = 0; jj < NW - 1; ++jj) {
            const int j = (NW - 1) - jj;         // j = 8..1 (compile-time)
            if (j <= m + 1)
                E[j] = lse2(E[j] + bm[m], wave_shr1(E[j - 1]) + lm[m]);
        }
        E[0] += bm[m];
    }

    if (lane <= TS) {
#pragma unroll
        for (int j = 0; j < NW; ++j)
            dstW[j * SU + lane] = (lane >= j) ? E[j] : NEG_INF;
    }
}

// ------- kernel 2: fused tail — compose (waves 0-4) + scan (wave 7) ---------
// One block per batch. Double-buffered LDS W-tile; __syncthreads per group.
__global__ __launch_bounds__(512) void tail_kernel(
    const float* __restrict__ lp_blank, const float* __restrict__ lp_label,
    const int* __restrict__ input_lengths, const int* __restrict__ label_lengths,
    float* __restrict__ out)
{
    __shared__ float Wlds[2][WGRP][NW][SU];   // 14.8 KB
    const int b    = blockIdx.x;
    const int wv   = threadIdx.x >> 6;
    const int lane = threadIdx.x & 63;

    // scan state (live only in wave 7; uniform setup is cheap)
    const int inlen  = input_lengths[b];
    const int lablen = label_lengths[b];
    const int rr     = inlen & (SS - 1);
    const int s_part = inlen >> 3;                   // tail-singles superstep
    const int s_cap  = (rr == 0) ? s_part - 1 : -1;  // capture-after superstep
    const int uu = (lane <= TS) ? lane : TS;
    const int ul = (lane >= 1 && lane <= TS) ? (lane - 1) : 0;
    const bool u_dead = (lane == 0 || lane > TS);
    float alpha = (lane == 0) ? 0.0f : NEG_INF;
    float saved = NEG_INF;

    // prologue: compose group 0 into buffer 0
    if (wv < WGRP) compose8(lp_blank, lp_label, b, wv, lane, &Wlds[0][wv][0][0]);
    __syncthreads();

    for (int g = 0; g < NGRP; ++g) {
        const int cur = g & 1;
        if (wv < WGRP && g + 1 < NGRP)
            compose8(lp_blank, lp_label, b, (g + 1) * WGRP + wv, lane,
                     &Wlds[cur ^ 1][wv][0][0]);
        if (wv == 7) {
            float w[WGRP * NW];
#pragma unroll
            for (int ss = 0; ss < WGRP; ++ss)
#pragma unroll
                for (int j = 0; j < NW; ++j)
                    w[ss * NW + j] = Wlds[cur][ss][j][uu];   // stride-1 in lane
#pragma unroll
            for (int ss = 0; ss < WGRP; ++ss) {
                const int s = g * WGRP + ss;
                if (rr && s == s_part) {   // general-length tail: rr single steps
                    float a2 = alpha;
#pragma unroll
                    for (int q = 0; q < SS - 1; ++q) {
                        if (q < rr) {
                            const int t = SS * s_part + q;
                            const float pbv = lp_blank[((size_t)b * TT + t) * SU + uu];
                            float plv = lp_label[((size_t)b * TT + t) * TS + ul];
                            plv = u_dead ? NEG_INF : plv;
                            a2 = lse2(a2 + pbv, wave_shr1(a2) + plv);
                        }
                    }
                    saved = a2;
                }
                const float s1 = wave_shr1(alpha), s2 = wave_shr1(s1);
                const float s3 = wave_shr1(s2),    s4 = wave_shr1(s3);
                const float s5 = wave_shr1(s4),    s6 = wave_shr1(s5);
                const float s7 = wave_shr1(s6),    s8 = wave_shr1(s7);
                const float T0 = alpha + w[ss * NW + 0];
                const float T1 = s1 + w[ss * NW + 1];
                const float T2 = s2 + w[ss * NW + 2];
                const float T3 = s3 + w[ss * NW + 3];
                const float T4 = s4 + w[ss * NW + 4];
                const float T5 = s5 + w[ss * NW + 5];
                const float T6 = s6 + w[ss * NW + 6];
                const float T7 = s7 + w[ss * NW + 7];
                const float T8 = s8 + w[ss * NW + 8];
                const float M = fmaxf(fmaxf(fmaxf(fmaxf(T0, T1), fmaxf(T2, T3)),
                                            fmaxf(fmaxf(T4, T5), fmaxf(T6, T7))), T8);
                const float sm =
                    ((__builtin_amdgcn_exp2f(T0 - M) + __builtin_amdgcn_exp2f(T1 - M))
                   + (__builtin_amdgcn_exp2f(T2 - M) + __builtin_amdgcn_exp2f(T3 - M)))
                  + ((__builtin_amdgcn_exp2f(T4 - M) + __builtin_amdgcn_exp2f(T5 - M))
                   + (__builtin_amdgcn_exp2f(T6 - M) + __builtin_amdgcn_exp2f(T7 - M)))
                  +   __builtin_amdgcn_exp2f(T8 - M);
                alpha = M + __builtin_amdgcn_logf(sm);
                if (s == s_cap) saved = alpha;
            }
        }
        __syncthreads();
    }

    if (wv == 7) {
        const float cost_alpha = __shfl(saved, lablen);
        if (lane == 0) out[b] = -cost_alpha * LN2;   // back to natural log
    }
}

extern "C" void kernel_launch(void* const* d_in, const int* in_sizes, int n_in,
                              void* d_out, int out_size, void* d_ws, size_t ws_size,
                              hipStream_t stream) {
    const float* acts          = (const float*)d_in[0];
    const int*   labels        = (const int*)d_in[1];
    const int*   input_lengths = (const int*)d_in[2];
    const int*   label_lengths = (const int*)d_in[3];
    float* out = (float*)d_out;

    float* lp_blank = (float*)d_ws;                          // NROWS floats
    float* lp_label = lp_blank + NROWS;                      // TB*TT*TS floats

    rowlse_kernel<<<NROWS / 4, 256, 0, stream>>>(acts, labels, lp_blank, lp_label);
    tail_kernel<<<TB, 512, 0, stream>>>(lp_blank, lp_label,
                                        input_lengths, label_lengths, out);
}

// Round 10
// 60.873 us; speedup vs baseline: 1.1097x; 1.1097x over previous
//
#include <hip/hip_runtime.h>

// Problem constants (match reference)
#define TB 8
#define TT 400
#define TS 40
#define TV 512
#define SU (TS + 1)          // 41
#define NROWS (TB * TT * SU) // 131200
#define SS 8                 // t-steps per superstep
#define NSS (TT / SS)        // 50 supersteps
#define HALF (NSS / 2)       // 25
#define NW (SS + 1)          // 9 path weights per superstep
#define NEG_INF (-1.0e30f)
#define INV_LN2 1.44269504088896341f
#define LN2 0.69314718055994531f

// VALU whole-wave shift-up-by-1 (DPP wave_shr:1); lane 0 sources 0 (harmless).
__device__ __forceinline__ float wave_shr1(float x) {
    return __int_as_float(
        __builtin_amdgcn_update_dpp(0, __float_as_int(x), 0x138, 0xf, 0xf, true));
}

// base-2 logaddexp (lp values live in log2 domain)
__device__ __forceinline__ float lse2(float a, float c) {
    const float mx = fmaxf(a, c), mn = fminf(a, c);
    return mx + __builtin_amdgcn_logf(1.0f + __builtin_amdgcn_exp2f(mn - mx));
}

// ---------------- kernel 1: per-row log-sum-exp (HBM-bound, ~40us) ----------
__global__ __launch_bounds__(256) void rowlse_kernel(
    const float* __restrict__ acts, const int* __restrict__ labels,
    float* __restrict__ lp_blank, float* __restrict__ lp_label)
{
    const int wave = threadIdx.x >> 6;
    const int lane = threadIdx.x & 63;
    const int row  = blockIdx.x * 4 + wave;   // grid*4 == NROWS exactly

    const float* rp = acts + (size_t)row * TV;
    float4 a = *(const float4*)(rp + lane * 8);
    float4 b = *(const float4*)(rp + lane * 8 + 4);

    float m = fmaxf(fmaxf(fmaxf(a.x, a.y), fmaxf(a.z, a.w)),
                    fmaxf(fmaxf(b.x, b.y), fmaxf(b.z, b.w)));
#pragma unroll
    for (int off = 1; off < 64; off <<= 1) m = fmaxf(m, __shfl_xor(m, off));

    float s = __expf(a.x - m) + __expf(a.y - m) + __expf(a.z - m) + __expf(a.w - m)
            + __expf(b.x - m) + __expf(b.y - m) + __expf(b.z - m) + __expf(b.w - m);
#pragma unroll
    for (int off = 1; off < 64; off <<= 1) s += __shfl_xor(s, off);

    const float logZ = m + logf(s);

    if (lane == 0) {
        const int u  = row % SU;
        const int bt = row / SU;
        lp_blank[row] = (a.x - logZ) * INV_LN2;          // log2 domain
        if (u < TS) {
            const int b_idx = bt / TT;
            const int col   = labels[b_idx * TS + u];
            lp_label[bt * TS + u] = (rp[col] - logZ) * INV_LN2;
        }
    }
}

// compose superstep s into E[NW] (registers). Identical math to R8 (absmax 0):
// in-register DP, E[j] <- LSE2( E[j]+b_m , shr1(E[j-1])+l_m ), j descending.
__device__ __forceinline__ void compose8_regs(
    const float* __restrict__ lp_blank, const float* __restrict__ lp_label,
    int b, int s, int lane, float* E)
{
    const int t0 = s * SS;
    const int uu = (lane <= TS) ? lane : TS;               // clamp loads
    const bool have_l = (lane >= 1 && lane <= TS);

    const float* pb = lp_blank + ((size_t)b * TT + t0) * SU + uu;
    const float* pl = lp_label + ((size_t)b * TT + t0) * TS + (have_l ? lane - 1 : 0);

    float bm[SS], lm[SS];
#pragma unroll
    for (int m = 0; m < SS; ++m) {
        bm[m] = pb[m * SU];
        float lv = pl[m * TS];
        lm[m] = have_l ? lv : NEG_INF;   // u=0 / u>TS: move-into-u invalid
    }

    E[0] = 0.0f;
#pragma unroll
    for (int j = 1; j < NW; ++j) E[j] = NEG_INF;

#pragma unroll
    for (int m = 0; m < SS; ++m) {
#pragma unroll
        for (int jj = 0; jj < NW - 1; ++jj) {
            const int j = (NW - 1) - jj;         // j = 8..1 (compile-time)
            if (j <= m + 1)
                E[j] = lse2(E[j] + bm[m], wave_shr1(E[j - 1]) + lm[m]);
        }
        E[0] += bm[m];
    }
}

__device__ __forceinline__ void store_E(const float* E, int lane, float* dst) {
    if (lane <= TS) {
#pragma unroll
        for (int j = 0; j < NW; ++j)
            dst[j * SU + lane] = (lane >= j) ? E[j] : NEG_INF;  // exact mask
    }
}

// ------- kernel 2: fused tail — burst compose + scan, LDS half-buffer -------
// One block per batch, 16 waves.
//  A: all waves compose supersteps 0..24 -> LDS.          (parallel burst)
//  B: wave 0 scans 0..24 from LDS  ||  waves 1..15 compose 25..49 into regs.
//  C: dump regs into the SAME LDS buffer; wave 0 scans 25..49.
__global__ __launch_bounds__(1024) void tail_kernel(
    const float* __restrict__ lp_blank, const float* __restrict__ lp_label,
    const int* __restrict__ input_lengths, const int* __restrict__ label_lengths,
    float* __restrict__ out)
{
    __shared__ float Wlds[HALF][NW][SU];   // 36.9 KB (< 64 KB static limit)
    const int b    = blockIdx.x;
    const int wv   = threadIdx.x >> 6;
    const int lane = threadIdx.x & 63;

    // scan state (used by wave 0; uniform setup is cheap everywhere)
    const int inlen  = input_lengths[b];
    const int lablen = label_lengths[b];
    const int rr     = inlen & (SS - 1);
    const int s_part = inlen >> 3;                   // tail-singles superstep
    const int s_cap  = (rr == 0) ? s_part - 1 : -1;  // capture-after superstep
    const int uu = (lane <= TS) ? lane : TS;
    const int ul = (lane >= 1 && lane <= TS) ? (lane - 1) : 0;
    const bool u_dead = (lane == 0 || lane > TS);
    float alpha = (lane == 0) ? 0.0f : NEG_INF;
    float saved = NEG_INF;

    // ---- phase A: burst-compose supersteps 0..24 into LDS ----
    for (int s = wv; s < HALF; s += 16) {
        float E[NW];
        compose8_regs(lp_blank, lp_label, b, s, lane, E);
        store_E(E, lane, &Wlds[s][0][0]);
    }
    __syncthreads();

#define LOADW(BUF, ss) { \
    _Pragma("unroll") \
    for (int j = 0; j < NW; ++j) (BUF)[j] = Wlds[(ss)][j][uu]; }

#define STEP(BUF, GS) { \
    const int gs = (GS); \
    if (rr && gs == s_part) {   /* general-length tail: rr single steps */ \
        float a2 = alpha; \
        _Pragma("unroll") \
        for (int q = 0; q < SS - 1; ++q) { \
            if (q < rr) { \
                const int t = SS * s_part + q; \
                const float pbv = lp_blank[((size_t)b * TT + t) * SU + uu]; \
                float plv = lp_label[((size_t)b * TT + t) * TS + ul]; \
                plv = u_dead ? NEG_INF : plv; \
                a2 = lse2(a2 + pbv, wave_shr1(a2) + plv); \
            } \
        } \
        saved = a2; \
    } \
    const float s1 = wave_shr1(alpha), s2 = wave_shr1(s1); \
    const float s3 = wave_shr1(s2),    s4 = wave_shr1(s3); \
    const float s5 = wave_shr1(s4),    s6 = wave_shr1(s5); \
    const float s7 = wave_shr1(s6),    s8 = wave_shr1(s7); \
    const float T0 = alpha + (BUF)[0]; \
    const float T1 = s1 + (BUF)[1]; \
    const float T2 = s2 + (BUF)[2]; \
    const float T3 = s3 + (BUF)[3]; \
    const float T4 = s4 + (BUF)[4]; \
    const float T5 = s5 + (BUF)[5]; \
    const float T6 = s6 + (BUF)[6]; \
    const float T7 = s7 + (BUF)[7]; \
    const float T8 = s8 + (BUF)[8]; \
    const float M = fmaxf(fmaxf(fmaxf(fmaxf(T0, T1), fmaxf(T2, T3)), \
                                fmaxf(fmaxf(T4, T5), fmaxf(T6, T7))), T8); \
    const float sm = ((__builtin_amdgcn_exp2f(T0 - M) + __builtin_amdgcn_exp2f(T1 - M)) \
                   +  (__builtin_amdgcn_exp2f(T2 - M) + __builtin_amdgcn_exp2f(T3 - M))) \
                   + ((__builtin_amdgcn_exp2f(T4 - M) + __builtin_amdgcn_exp2f(T5 - M)) \
                   +  (__builtin_amdgcn_exp2f(T6 - M) + __builtin_amdgcn_exp2f(T7 - M))) \
                   +   __builtin_amdgcn_exp2f(T8 - M); \
    alpha = M + __builtin_amdgcn_logf(sm); \
    if (gs == s_cap) saved = alpha; }

#define SCAN_HALF(BASE) { \
    float wA[NW], wB[NW]; \
    LOADW(wA, 0); \
    for (int i = 0; i < 12; ++i) { \
        const int ss0 = 2 * i; \
        LOADW(wB, ss0 + 1); \
        STEP(wA, (BASE) + ss0); \
        LOADW(wA, ss0 + 2); \
        STEP(wB, (BASE) + ss0 + 1); \
    } \
    STEP(wA, (BASE) + HALF - 1); }

    // ---- phase B: wave 0 scans half 1; waves 1..15 compose half 2 to regs --
    float Er0[NW], Er1[NW];
    int nm = 0, sm0 = 0, sm1 = 0;
    if (wv == 0) {
        SCAN_HALF(0);
    } else {
        for (int s = HALF + (wv - 1); s < NSS; s += 15) {
            if (nm == 0) { compose8_regs(lp_blank, lp_label, b, s, lane, Er0); sm0 = s; }
            else         { compose8_regs(lp_blank, lp_label, b, s, lane, Er1); sm1 = s; }
            ++nm;
        }
    }
    __syncthreads();   // scan1 done reading; safe to overwrite Wlds

    if (wv != 0) {
        if (nm >= 1) store_E(Er0, lane, &Wlds[sm0 - HALF][0][0]);
        if (nm >= 2) store_E(Er1, lane, &Wlds[sm1 - HALF][0][0]);
    }
    __syncthreads();   // half-2 W visible

    // ---- phase C: wave 0 scans half 2; others exit ----
    if (wv == 0) {
        SCAN_HALF(HALF);
        const float cost_alpha = __shfl(saved, lablen);
        if (lane == 0) out[b] = -cost_alpha * LN2;   // back to natural log
    }

#undef LOADW
#undef STEP
#undef SCAN_HALF
}

extern "C" void kernel_launch(void* const* d_in, const int* in_sizes, int n_in,
                              void* d_out, int out_size, void* d_ws, size_t ws_size,
                              hipStream_t stream) {
    const float* acts          = (const float*)d_in[0];
    const int*   labels        = (const int*)d_in[1];
    const int*   input_lengths = (const int*)d_in[2];
    const int*   label_lengths = (const int*)d_in[3];
    float* out = (float*)d_out;

    float* lp_blank = (float*)d_ws;                          // NROWS floats
    float* lp_label = lp_blank + NROWS;                      // TB*TT*TS floats

    rowlse_kernel<<<NROWS / 4, 256, 0, stream>>>(acts, labels, lp_blank, lp_label);
    tail_kernel<<<TB, 1024, 0, stream>>>(lp_blank, lp_label,
                                         input_lengths, label_lengths, out);
}